// Round 6
// baseline (256.916 us; speedup 1.0000x reference)
//
#include <hip/hip_runtime.h>

#define N_NODES 100000
#define N_EDGES 1600000
#define EMBED_DIM 64

// ---------- flat-CSR path ----------
#define CAP_ROW 32                                // slots per row (Poisson(16); P(deg>32)~9e-5)
#define OVCAP 8192                                // overflow backstop

// ---------- legacy bucket path (fallback when ws < flat need) ----------
#define RPB 256                                   // rows per bucket
#define NBKT ((N_NODES + RPB - 1) / RPB)          // 391
#define CAP 4608                                  // slots per bucket
#define TILE 4096                                 // edges per binA block
#define NTILE ((N_EDGES + TILE - 1) / TILE)       // 391

// ============================ FLAT-CSR PATH ============================
// One scan-free scatter replaces binA+binB (~100us of barrier/latency-bound
// preprocessing). p = atomicAdd(cnt[r]); packed[r*32+p] = (col,val).
// Scattered 8B writes absorbed by L2 RMW; HBM ~19MB read + ~25MB write.
__global__ __launch_bounds__(256) void k_scatter_flat(const int* __restrict__ rows,
                                                      const int* __restrict__ cols,
                                                      const float* __restrict__ vals,
                                                      int* __restrict__ cnt,
                                                      int2* __restrict__ packed,
                                                      int* __restrict__ ov_cnt,
                                                      int4* __restrict__ ov) {
    for (int e = blockIdx.x * 256 + threadIdx.x; e < N_EDGES; e += 256 * 2048) {
        int r = rows[e];
        int p = atomicAdd(&cnt[r], 1);
        if (p < CAP_ROW) {
            packed[(size_t)r * CAP_ROW + p] = make_int2(cols[e], __float_as_int(vals[e]));
        } else {
            int ovi = atomicAdd(ov_cnt, 1);
            if (ovi < OVCAP) ov[ovi] = make_int4(r, cols[e], __float_as_int(vals[e]), 0);
        }
    }
}

// gather, flat layout: deg<=32 -> single window, no while loop.
__global__ __launch_bounds__(256) void k_gather_flat(const float* __restrict__ x,
                                                     const int* __restrict__ cnt,
                                                     const int* __restrict__ pw,
                                                     float* __restrict__ out) {
    int wid = (blockIdx.x * 256 + threadIdx.x) >> 6;
    int lane = threadIdx.x & 63;
    if (wid >= N_NODES) return;
    int deg = cnt[wid];
    if (deg > CAP_ROW) deg = CAP_ROW;
    int w = 0;
    if (lane < 2 * deg) w = pw[2 * CAP_ROW * wid + lane];
    float acc = 0.f;
    for (int k0 = 0; k0 < deg; k0 += 16) {
#pragma unroll
        for (int k = 0; k < 16; ++k) {
            int kk = k0 + k;
            int cpack = __builtin_amdgcn_readlane(w, 2 * kk);
            float v = __int_as_float(__builtin_amdgcn_readlane(w, 2 * kk + 1));
            // lanes >= 2*deg hold w=0 -> v=0 -> harmless +0
            acc += v * x[(cpack & 0x1FFFF) * EMBED_DIM + lane];
        }
    }
    out[wid * EMBED_DIM + lane] = acc;
}

// ---------- overflow cleanup (runs after gather; expected n ~ 10) ----------
__global__ __launch_bounds__(256) void k_overflow(const float* __restrict__ x,
                                                  const int* __restrict__ ov_cnt,
                                                  const int4* __restrict__ ov,
                                                  float* __restrict__ out) {
    int n = *ov_cnt;
    if (n > OVCAP) n = OVCAP;
    int lane = threadIdx.x & 63;
    int wglobal = (blockIdx.x * 256 + threadIdx.x) >> 6;
    for (int i = wglobal; i < n; i += 64 * 4) {
        int4 e = ov[i];
        atomicAdd(&out[e.x * EMBED_DIM + lane],
                  __int_as_float(e.z) * x[e.y * EMBED_DIM + lane]);
    }
}

// ============================ LEGACY BUCKET PATH ============================
__global__ __launch_bounds__(512) void k_binA(const int* __restrict__ rows,
                                              const int* __restrict__ cols,
                                              const float* __restrict__ vals,
                                              int* __restrict__ gcur,
                                              int2* __restrict__ packed,
                                              int* __restrict__ ov_cnt,
                                              int4* __restrict__ ov) {
    __shared__ int hist[NBKT];
    __shared__ int off[NBKT];
    __shared__ int cur[NBKT];
    __shared__ int gbase[NBKT];
    __shared__ int wsum[8];
    __shared__ int stotal;
    __shared__ int2 stage[TILE];   // 32 KB
    __shared__ int dg[TILE];       // 16 KB
    const int tid = threadIdx.x;
    const int lane = tid & 63;
    const int wid = tid >> 6;      // 0..7
    const int e0 = blockIdx.x * TILE;

    for (int i = tid; i < NBKT; i += 512) hist[i] = 0;
    __syncthreads();

    for (int i = tid; i < TILE; i += 512) {
        int e = e0 + i;
        if (e < N_EDGES) atomicAdd(&hist[rows[e] >> 8], 1);
    }
    __syncthreads();

    int v = (tid < NBKT) ? hist[tid] : 0;
    int incl = v;
    for (int o = 1; o < 64; o <<= 1) {
        int t = __shfl_up(incl, o, 64);
        if (lane >= o) incl += t;
    }
    if (lane == 63) wsum[wid] = incl;
    __syncthreads();
    if (wid == 0 && lane < 8) {
        int s = wsum[lane];
        int si = s;
        for (int o = 1; o < 8; o <<= 1) {
            int t = __shfl_up(si, o, 64);
            if (lane >= o) si += t;
        }
        wsum[lane] = si - s;
        if (lane == 7) stotal = si;
    }
    __syncthreads();
    int excl = incl - v + wsum[wid];
    if (tid < NBKT) { off[tid] = excl; cur[tid] = excl; }

    for (int b = tid; b < NBKT; b += 512) {
        int c = hist[b];
        gbase[b] = c ? atomicAdd(&gcur[b], c) : 0;
    }
    __syncthreads();

    for (int i = tid; i < TILE; i += 512) {
        int e = e0 + i;
        if (e < N_EDGES) {
            int r = rows[e];
            int b = r >> 8;
            int p = atomicAdd(&cur[b], 1);
            stage[p] = make_int2(((r & (RPB - 1)) << 17) | cols[e],
                                 __float_as_int(vals[e]));
            int d = gbase[b] + (p - off[b]);
            dg[p] = (d < CAP) ? (b * CAP + d) : (0x40000000 | b);
        }
    }
    __syncthreads();

    int total = stotal;
    for (int j = tid; j < total; j += 512) {
        int d = dg[j];
        int2 ev = stage[j];
        if (d & 0x40000000) {
            int b = d & 0xFFFF;
            int ovi = atomicAdd(ov_cnt, 1);
            if (ovi < OVCAP) {
                int r = b * RPB + (((unsigned)ev.x) >> 17);
                ov[ovi] = make_int4(r, ev.x & 0x1FFFF, ev.y, 0);
            }
        } else {
            packed[d] = ev;
        }
    }
}

__global__ __launch_bounds__(512) void k_binB(const int* __restrict__ gcur,
                                              int2* __restrict__ packed,
                                              int* __restrict__ row_ptr,
                                              int* __restrict__ cnt) {
    __shared__ int2 stage[CAP];    // 36 KB
    __shared__ int h[RPB];
    __shared__ int cur[RPB];
    __shared__ int wsum[4];
    const int b = blockIdx.x;
    const int tid = threadIdx.x;
    const int lane = tid & 63;
    const int wid = tid >> 6;
    int n = gcur[b];
    if (n > CAP) n = CAP;
    const int base = b * CAP;

    if (tid < RPB) h[tid] = 0;
    __syncthreads();
    for (int j = tid; j < n; j += 512) {
        int2 e = packed[base + j];
        stage[j] = e;
        atomicAdd(&h[((unsigned)e.x) >> 17], 1);
    }
    __syncthreads();

    int hv = (tid < RPB) ? h[tid] : 0;
    int incl = hv;
    for (int o = 1; o < 64; o <<= 1) {
        int t = __shfl_up(incl, o, 64);
        if (lane >= o) incl += t;
    }
    if (tid < RPB && lane == 63) wsum[wid] = incl;
    __syncthreads();
    if (wid == 0 && lane < 4) {
        int s = wsum[lane];
        int si = s;
        for (int o = 1; o < 4; o <<= 1) {
            int t = __shfl_up(si, o, 64);
            if (lane >= o) si += t;
        }
        wsum[lane] = si - s;
    }
    __syncthreads();
    if (tid < RPB) {
        int ofs = incl - hv + wsum[wid];
        cur[tid] = ofs;
        int r = b * RPB + tid;
        if (r < N_NODES) {
            row_ptr[r] = base + ofs;
            cnt[r] = hv;
        }
    }
    __syncthreads();

    for (int j = tid; j < n; j += 512) {
        int2 e = stage[j];
        int lr = ((unsigned)e.x) >> 17;
        int p = atomicAdd(&cur[lr], 1);
        packed[base + p] = e;
    }
}

__global__ __launch_bounds__(256) void k_gather(const float* __restrict__ x,
                                                const int* __restrict__ row_ptr,
                                                const int* __restrict__ cnt,
                                                const int* __restrict__ pw,
                                                float* __restrict__ out) {
    int wid = (blockIdx.x * 256 + threadIdx.x) >> 6;
    int lane = threadIdx.x & 63;
    if (wid >= N_NODES) return;
    int beg = row_ptr[wid];
    int deg = cnt[wid];
    float acc = 0.f;
    int done = 0;
    while (done < deg) {
        int win = deg - done;
        if (win > 32) win = 32;
        int w = 0;
        if (lane < 2 * win) w = pw[2 * (beg + done) + lane];
        for (int k0 = 0; k0 < win; k0 += 16) {
#pragma unroll
            for (int k = 0; k < 16; ++k) {
                int kk = k0 + k;
                int cpack = __builtin_amdgcn_readlane(w, 2 * kk);
                float v = __int_as_float(__builtin_amdgcn_readlane(w, 2 * kk + 1));
                acc += v * x[(cpack & 0x1FFFF) * EMBED_DIM + lane];
            }
        }
        done += win;
    }
    out[wid * EMBED_DIM + lane] = acc;
}

// ---------- fallback (ws too small): atomic scatter ----------
__global__ __launch_bounds__(256) void spmm_scatter_kernel(
    const float* __restrict__ x, const float* __restrict__ vals,
    const int* __restrict__ rows, const int* __restrict__ cols,
    float* __restrict__ out) {
    const int wave_in_block = threadIdx.x >> 6;
    const int lane = threadIdx.x & 63;
    const int e = blockIdx.x * 4 + wave_in_block;
    if (e >= N_EDGES) return;
    const float m = vals[e] * x[cols[e] * EMBED_DIM + lane];
    atomicAdd(&out[rows[e] * EMBED_DIM + lane], m);
}

extern "C" void kernel_launch(void* const* d_in, const int* in_sizes, int n_in,
                              void* d_out, int out_size, void* d_ws, size_t ws_size,
                              hipStream_t stream) {
    const float* x    = (const float*)d_in[0];
    const float* vals = (const float*)d_in[1];
    const int*   rows = (const int*)d_in[2];
    const int*   cols = (const int*)d_in[3];
    float* out = (float*)d_out;

    // ---- tier 1: flat CSR (packed[N*32] int2 | ov[OVCAP] int4 | cnt[N] | ov_cnt) ----
    const size_t flat_packed_b = (size_t)N_NODES * CAP_ROW * 8;   // 25,600,000
    const size_t ov_b          = (size_t)OVCAP * 16;
    const size_t flat_need = flat_packed_b + ov_b + ((size_t)N_NODES + 1) * 4;
    if (ws_size >= flat_need) {
        int2* packed = (int2*)d_ws;
        int4* ov     = (int4*)((char*)d_ws + flat_packed_b);
        int*  cnt    = (int*)((char*)d_ws + flat_packed_b + ov_b);
        int*  ov_cnt = cnt + N_NODES;

        hipMemsetAsync(cnt, 0, ((size_t)N_NODES + 1) * sizeof(int), stream);
        k_scatter_flat<<<2048, 256, 0, stream>>>(rows, cols, vals, cnt, packed, ov_cnt, ov);
        k_gather_flat<<<(N_NODES * 64 + 255) / 256, 256, 0, stream>>>(x, cnt, (const int*)packed, out);
        k_overflow<<<64, 256, 0, stream>>>(x, ov_cnt, ov, out);
        return;
    }

    // ---- tier 2: legacy bucket pipeline (verified, 173us) ----
    const size_t packed_b = (size_t)NBKT * CAP * 8;
    const size_t need = packed_b + ov_b + ((size_t)NBKT + 1 + 2 * (size_t)N_NODES) * 4;
    if (ws_size < need) {
        hipMemsetAsync(out, 0, (size_t)out_size * sizeof(float), stream);
        spmm_scatter_kernel<<<(N_EDGES + 3) / 4, 256, 0, stream>>>(x, vals, rows, cols, out);
        return;
    }

    int2* packed  = (int2*)d_ws;
    int4* ov      = (int4*)((char*)d_ws + packed_b);
    int*  gcur    = (int*)((char*)d_ws + packed_b + ov_b);
    int*  ov_cnt  = gcur + NBKT;
    int*  row_ptr = ov_cnt + 1;
    int*  cnt     = row_ptr + N_NODES;

    hipMemsetAsync(gcur, 0, ((size_t)NBKT + 1) * sizeof(int), stream);

    k_binA<<<NTILE, 512, 0, stream>>>(rows, cols, vals, gcur, packed, ov_cnt, ov);
    k_binB<<<NBKT, 512, 0, stream>>>(gcur, packed, row_ptr, cnt);
    k_gather<<<(N_NODES * 64 + 255) / 256, 256, 0, stream>>>(x, row_ptr, cnt, (const int*)packed, out);
    k_overflow<<<64, 256, 0, stream>>>(x, ov_cnt, ov, out);
}

// Round 7
// 177.400 us; speedup vs baseline: 1.4482x; 1.4482x over previous
//
#include <hip/hip_runtime.h>

#define N_NODES 100000
#define N_EDGES 1600000
#define EMBED_DIM 64

#define RPB 256                                   // rows per bucket
#define NBKT ((N_NODES + RPB - 1) / RPB)          // 391
#define CAP 4608                                  // slots per bucket (mean 4092, +8 sigma)
#define TILE 4096                                 // edges per binA block
#define NTILE ((N_EDGES + TILE - 1) / TILE)       // 391
#define OVCAP 8192                                // overflow backstop

#define BG_THREADS 1024
#define EPT ((CAP + BG_THREADS - 1) / BG_THREADS) // 5 edges/thread in registers

// ---------- pass A: tile counting-sort into bucket regions (dense writes) ----------
// (verified r5 version: 512 threads, wave-shfl scan)
__global__ __launch_bounds__(512) void k_binA(const int* __restrict__ rows,
                                              const int* __restrict__ cols,
                                              const float* __restrict__ vals,
                                              int* __restrict__ gcur,
                                              int2* __restrict__ packed,
                                              int* __restrict__ ov_cnt,
                                              int4* __restrict__ ov) {
    __shared__ int hist[NBKT];
    __shared__ int off[NBKT];
    __shared__ int cur[NBKT];
    __shared__ int gbase[NBKT];
    __shared__ int wsum[8];
    __shared__ int stotal;
    __shared__ int2 stage[TILE];   // 32 KB
    __shared__ int dg[TILE];       // 16 KB
    const int tid = threadIdx.x;
    const int lane = tid & 63;
    const int wid = tid >> 6;      // 0..7
    const int e0 = blockIdx.x * TILE;

    for (int i = tid; i < NBKT; i += 512) hist[i] = 0;
    __syncthreads();

    for (int i = tid; i < TILE; i += 512) {
        int e = e0 + i;
        if (e < N_EDGES) atomicAdd(&hist[rows[e] >> 8], 1);
    }
    __syncthreads();

    int v = (tid < NBKT) ? hist[tid] : 0;
    int incl = v;
    for (int o = 1; o < 64; o <<= 1) {
        int t = __shfl_up(incl, o, 64);
        if (lane >= o) incl += t;
    }
    if (lane == 63) wsum[wid] = incl;
    __syncthreads();
    if (wid == 0 && lane < 8) {
        int s = wsum[lane];
        int si = s;
        for (int o = 1; o < 8; o <<= 1) {
            int t = __shfl_up(si, o, 64);
            if (lane >= o) si += t;
        }
        wsum[lane] = si - s;
        if (lane == 7) stotal = si;
    }
    __syncthreads();
    int excl = incl - v + wsum[wid];
    if (tid < NBKT) { off[tid] = excl; cur[tid] = excl; }

    for (int b = tid; b < NBKT; b += 512) {
        int c = hist[b];
        gbase[b] = c ? atomicAdd(&gcur[b], c) : 0;
    }
    __syncthreads();

    for (int i = tid; i < TILE; i += 512) {
        int e = e0 + i;
        if (e < N_EDGES) {
            int r = rows[e];
            int b = r >> 8;
            int p = atomicAdd(&cur[b], 1);
            stage[p] = make_int2(((r & (RPB - 1)) << 17) | cols[e],
                                 __float_as_int(vals[e]));
            int d = gbase[b] + (p - off[b]);
            dg[p] = (d < CAP) ? (b * CAP + d) : (0x40000000 | b);
        }
    }
    __syncthreads();

    int total = stotal;
    for (int j = tid; j < total; j += 512) {
        int d = dg[j];
        int2 ev = stage[j];
        if (d & 0x40000000) {
            int b = d & 0xFFFF;
            int ovi = atomicAdd(ov_cnt, 1);
            if (ovi < OVCAP) {
                int r = b * RPB + (((unsigned)ev.x) >> 17);
                ov[ovi] = make_int4(r, ev.x & 0x1FFFF, ev.y, 0);
            }
        } else {
            packed[d] = ev;
        }
    }
}

// ---------- fused binB+gather: one block per bucket ----------
// Load bucket edges into REGISTERS (5/thread) while histogramming rows in LDS;
// wave-shfl scan; place into single LDS stage[] row-sorted (regs are the
// source -> no double buffer); then 16 waves x 16 rows register-accumulate
// gather reading edge words from LDS. Kills binB's 25.6MB packed round-trip
// + one dispatch + row_ptr/cnt arrays.
// LDS ~40KB -> 2 blocks/CU (32 waves) co-resident for x-gather TLP.
__global__ __launch_bounds__(BG_THREADS) void k_bg(const float* __restrict__ x,
                                                   const int* __restrict__ gcur,
                                                   const int2* __restrict__ packed,
                                                   float* __restrict__ out) {
    __shared__ int2 stage[CAP];    // 36 KB
    __shared__ int h[RPB];
    __shared__ int ofs[RPB];
    __shared__ int cur[RPB];
    __shared__ int wsum[4];
    const int b = blockIdx.x;
    const int tid = threadIdx.x;
    const int lane = tid & 63;
    const int wid = tid >> 6;      // 0..15
    int n = gcur[b];
    if (n > CAP) n = CAP;
    const int base = b * CAP;

    if (tid < RPB) h[tid] = 0;
    __syncthreads();

    // load edges into registers + histogram rows
    int2 ereg[EPT];
    int lr[EPT];
#pragma unroll
    for (int jj = 0; jj < EPT; ++jj) {
        int j = tid + jj * BG_THREADS;
        lr[jj] = -1;
        if (j < n) {
            int2 e = packed[base + j];
            ereg[jj] = e;
            int r = ((unsigned)e.x) >> 17;
            lr[jj] = r;
            atomicAdd(&h[r], 1);
        }
    }
    __syncthreads();

    // exclusive scan h[0..255] (waves 0..3)
    int hv = (tid < RPB) ? h[tid] : 0;
    int incl = hv;
    for (int o = 1; o < 64; o <<= 1) {
        int t = __shfl_up(incl, o, 64);
        if (lane >= o) incl += t;
    }
    if (tid < RPB && lane == 63) wsum[wid] = incl;
    __syncthreads();
    if (wid == 0 && lane < 4) {
        int s = wsum[lane];
        int si = s;
        for (int o = 1; o < 4; o <<= 1) {
            int t = __shfl_up(si, o, 64);
            if (lane >= o) si += t;
        }
        wsum[lane] = si - s;
    }
    __syncthreads();
    if (tid < RPB) {
        int o2 = incl - hv + wsum[wid];
        ofs[tid] = o2;
        cur[tid] = o2;
    }
    __syncthreads();

    // place row-sorted into LDS (source = registers -> no RAW hazard)
#pragma unroll
    for (int jj = 0; jj < EPT; ++jj) {
        if (lr[jj] >= 0) {
            int p = atomicAdd(&cur[lr[jj]], 1);
            stage[p] = ereg[jj];
        }
    }
    __syncthreads();

    // gather: wave wid handles rows wid*16 .. wid*16+15
    const int* sw = (const int*)stage;
    for (int i = 0; i < 16; ++i) {
        int r = wid * 16 + i;
        int grow = b * RPB + r;
        if (grow >= N_NODES) break;
        int deg = h[r];
        int beg = ofs[r];
        float acc = 0.f;
        int done = 0;
        while (done < deg) {
            int win = deg - done;
            if (win > 32) win = 32;
            int w = 0;
            if (lane < 2 * win) w = sw[((beg + done) << 1) + lane];
            for (int k0 = 0; k0 < win; k0 += 16) {
#pragma unroll
                for (int k = 0; k < 16; ++k) {
                    int kk = k0 + k;
                    int cpack = __builtin_amdgcn_readlane(w, 2 * kk);
                    float v = __int_as_float(__builtin_amdgcn_readlane(w, 2 * kk + 1));
                    acc += v * x[(cpack & 0x1FFFF) * EMBED_DIM + lane];
                }
            }
            done += win;
        }
        out[(size_t)grow * EMBED_DIM + lane] = acc;
    }
}

// ---------- overflow cleanup (runs after gather; expected n==0) ----------
__global__ __launch_bounds__(256) void k_overflow(const float* __restrict__ x,
                                                  const int* __restrict__ ov_cnt,
                                                  const int4* __restrict__ ov,
                                                  float* __restrict__ out) {
    int n = *ov_cnt;
    if (n > OVCAP) n = OVCAP;
    int lane = threadIdx.x & 63;
    int wglobal = (blockIdx.x * 256 + threadIdx.x) >> 6;
    for (int i = wglobal; i < n; i += 64 * 4) {
        int4 e = ov[i];
        atomicAdd(&out[e.x * EMBED_DIM + lane],
                  __int_as_float(e.z) * x[e.y * EMBED_DIM + lane]);
    }
}

// ---------- fallback (ws too small): atomic scatter ----------
__global__ __launch_bounds__(256) void spmm_scatter_kernel(
    const float* __restrict__ x, const float* __restrict__ vals,
    const int* __restrict__ rows, const int* __restrict__ cols,
    float* __restrict__ out) {
    const int wave_in_block = threadIdx.x >> 6;
    const int lane = threadIdx.x & 63;
    const int e = blockIdx.x * 4 + wave_in_block;
    if (e >= N_EDGES) return;
    const float m = vals[e] * x[cols[e] * EMBED_DIM + lane];
    atomicAdd(&out[rows[e] * EMBED_DIM + lane], m);
}

extern "C" void kernel_launch(void* const* d_in, const int* in_sizes, int n_in,
                              void* d_out, int out_size, void* d_ws, size_t ws_size,
                              hipStream_t stream) {
    const float* x    = (const float*)d_in[0];
    const float* vals = (const float*)d_in[1];
    const int*   rows = (const int*)d_in[2];
    const int*   cols = (const int*)d_in[3];
    float* out = (float*)d_out;

    // ws layout: packed[NBKT*CAP] int2 | ov[OVCAP] int4 | gcur[NBKT] | ov_cnt
    const size_t packed_b = (size_t)NBKT * CAP * 8;         // 14,413,824 (16B-aligned)
    const size_t ov_b     = (size_t)OVCAP * 16;
    const size_t need = packed_b + ov_b + ((size_t)NBKT + 1) * 4;
    if (ws_size < need) {
        hipMemsetAsync(out, 0, (size_t)out_size * sizeof(float), stream);
        spmm_scatter_kernel<<<(N_EDGES + 3) / 4, 256, 0, stream>>>(x, vals, rows, cols, out);
        return;
    }

    int2* packed  = (int2*)d_ws;
    int4* ov      = (int4*)((char*)d_ws + packed_b);
    int*  gcur    = (int*)((char*)d_ws + packed_b + ov_b);
    int*  ov_cnt  = gcur + NBKT;

    // single memset: gcur[NBKT] + ov_cnt adjacent
    hipMemsetAsync(gcur, 0, ((size_t)NBKT + 1) * sizeof(int), stream);

    k_binA<<<NTILE, 512, 0, stream>>>(rows, cols, vals, gcur, packed, ov_cnt, ov);
    k_bg<<<NBKT, BG_THREADS, 0, stream>>>(x, gcur, (const int2*)packed, out);
    k_overflow<<<64, 256, 0, stream>>>(x, ov_cnt, ov, out);
}

// Round 8
// 170.496 us; speedup vs baseline: 1.5069x; 1.0405x over previous
//
#include <hip/hip_runtime.h>

#define N_NODES 100000
#define N_EDGES 1600000
#define EMBED_DIM 64

#define RPB 256                                   // rows per bucket
#define NBKT ((N_NODES + RPB - 1) / RPB)          // 391
#define CAP 4608                                  // slots per bucket (mean 4092, +8 sigma)
#define TILE 4096                                 // edges per binA block
#define NTILE ((N_EDGES + TILE - 1) / TILE)       // 391
#define OVCAP 8192                                // overflow backstop

#define BG_THREADS 1024
#define EPT ((CAP + BG_THREADS - 1) / BG_THREADS) // 5 edges/thread in registers

// ---------- pass A: tile counting-sort into bucket regions (dense writes) ----------
// (verified r5 version: 512 threads, wave-shfl scan)
__global__ __launch_bounds__(512) void k_binA(const int* __restrict__ rows,
                                              const int* __restrict__ cols,
                                              const float* __restrict__ vals,
                                              int* __restrict__ gcur,
                                              int2* __restrict__ packed,
                                              int* __restrict__ ov_cnt,
                                              int4* __restrict__ ov) {
    __shared__ int hist[NBKT];
    __shared__ int off[NBKT];
    __shared__ int cur[NBKT];
    __shared__ int gbase[NBKT];
    __shared__ int wsum[8];
    __shared__ int stotal;
    __shared__ int2 stage[TILE];   // 32 KB
    __shared__ int dg[TILE];       // 16 KB
    const int tid = threadIdx.x;
    const int lane = tid & 63;
    const int wid = tid >> 6;      // 0..7
    const int e0 = blockIdx.x * TILE;

    for (int i = tid; i < NBKT; i += 512) hist[i] = 0;
    __syncthreads();

    for (int i = tid; i < TILE; i += 512) {
        int e = e0 + i;
        if (e < N_EDGES) atomicAdd(&hist[rows[e] >> 8], 1);
    }
    __syncthreads();

    int v = (tid < NBKT) ? hist[tid] : 0;
    int incl = v;
    for (int o = 1; o < 64; o <<= 1) {
        int t = __shfl_up(incl, o, 64);
        if (lane >= o) incl += t;
    }
    if (lane == 63) wsum[wid] = incl;
    __syncthreads();
    if (wid == 0 && lane < 8) {
        int s = wsum[lane];
        int si = s;
        for (int o = 1; o < 8; o <<= 1) {
            int t = __shfl_up(si, o, 64);
            if (lane >= o) si += t;
        }
        wsum[lane] = si - s;
        if (lane == 7) stotal = si;
    }
    __syncthreads();
    int excl = incl - v + wsum[wid];
    if (tid < NBKT) { off[tid] = excl; cur[tid] = excl; }

    for (int b = tid; b < NBKT; b += 512) {
        int c = hist[b];
        gbase[b] = c ? atomicAdd(&gcur[b], c) : 0;
    }
    __syncthreads();

    for (int i = tid; i < TILE; i += 512) {
        int e = e0 + i;
        if (e < N_EDGES) {
            int r = rows[e];
            int b = r >> 8;
            int p = atomicAdd(&cur[b], 1);
            stage[p] = make_int2(((r & (RPB - 1)) << 17) | cols[e],
                                 __float_as_int(vals[e]));
            int d = gbase[b] + (p - off[b]);
            dg[p] = (d < CAP) ? (b * CAP + d) : (0x40000000 | b);
        }
    }
    __syncthreads();

    int total = stotal;
    for (int j = tid; j < total; j += 512) {
        int d = dg[j];
        int2 ev = stage[j];
        if (d & 0x40000000) {
            int b = d & 0xFFFF;
            int ovi = atomicAdd(ov_cnt, 1);
            if (ovi < OVCAP) {
                int r = b * RPB + (((unsigned)ev.x) >> 17);
                ov[ovi] = make_int4(r, ev.x & 0x1FFFF, ev.y, 0);
            }
        } else {
            packed[d] = ev;
        }
    }
}

// ---------- fused binB+gather: one block per bucket ----------
// Staging identical to r7 (verified). Gather phase rewritten:
//  - edge words read from LDS stage[] via ds_read_b64 broadcast (no pw
//    cooperative load, no readlane -> ~2 VALU insts/edge saved)
//  - EMBED split across lane halves: lanes 0-31 = even edges, 32-63 = odd
//    edges, each lane owns a float2 dim-pair -> loads+FMAs per edge halved
//  - 8 independent x-loads batched per iteration (MLP)
//  - end of row: shfl_xor(32) combine, lanes 0-31 write float2 (coalesced)
__global__ __launch_bounds__(BG_THREADS) void k_bg(const float* __restrict__ x,
                                                   const int* __restrict__ gcur,
                                                   const int2* __restrict__ packed,
                                                   float* __restrict__ out) {
    __shared__ int2 stage[CAP];    // 36 KB
    __shared__ int h[RPB];
    __shared__ int ofs[RPB];
    __shared__ int cur[RPB];
    __shared__ int wsum[4];
    const int b = blockIdx.x;
    const int tid = threadIdx.x;
    const int lane = tid & 63;
    const int wid = tid >> 6;      // 0..15
    int n = gcur[b];
    if (n > CAP) n = CAP;
    const int base = b * CAP;

    if (tid < RPB) h[tid] = 0;
    __syncthreads();

    // load edges into registers + histogram rows
    int2 ereg[EPT];
    int lr[EPT];
#pragma unroll
    for (int jj = 0; jj < EPT; ++jj) {
        int j = tid + jj * BG_THREADS;
        lr[jj] = -1;
        if (j < n) {
            int2 e = packed[base + j];
            ereg[jj] = e;
            int r = ((unsigned)e.x) >> 17;
            lr[jj] = r;
            atomicAdd(&h[r], 1);
        }
    }
    __syncthreads();

    // exclusive scan h[0..255] (waves 0..3)
    int hv = (tid < RPB) ? h[tid] : 0;
    int incl = hv;
    for (int o = 1; o < 64; o <<= 1) {
        int t = __shfl_up(incl, o, 64);
        if (lane >= o) incl += t;
    }
    if (tid < RPB && lane == 63) wsum[wid] = incl;
    __syncthreads();
    if (wid == 0 && lane < 4) {
        int s = wsum[lane];
        int si = s;
        for (int o = 1; o < 4; o <<= 1) {
            int t = __shfl_up(si, o, 64);
            if (lane >= o) si += t;
        }
        wsum[lane] = si - s;
    }
    __syncthreads();
    if (tid < RPB) {
        int o2 = incl - hv + wsum[wid];
        ofs[tid] = o2;
        cur[tid] = o2;
    }
    __syncthreads();

    // place row-sorted into LDS (source = registers -> no RAW hazard)
#pragma unroll
    for (int jj = 0; jj < EPT; ++jj) {
        if (lr[jj] >= 0) {
            int p = atomicAdd(&cur[lr[jj]], 1);
            stage[p] = ereg[jj];
        }
    }
    __syncthreads();

    // gather: wave wid handles rows wid*16 .. wid*16+15
    const int half = lane >> 5;    // 0: even edges, 1: odd edges
    const int hl = lane & 31;      // dim-pair index
    const float2* __restrict__ x2 = (const float2*)x;
    for (int i = 0; i < 16; ++i) {
        int r = wid * 16 + i;
        int grow = b * RPB + r;
        if (grow >= N_NODES) break;
        int deg = h[r];
        int beg = ofs[r];
        float ax = 0.f, ay = 0.f;
        for (int j0 = 0; j0 < deg; j0 += 16) {
            float vv[8];
            float2 xv[8];
#pragma unroll
            for (int k = 0; k < 8; ++k) {
                int j = j0 + 2 * k + half;
                int2 e = (j < deg) ? stage[beg + j] : make_int2(0, 0);
                vv[k] = __int_as_float(e.y);               // 0 for pad
                xv[k] = x2[(e.x & 0x1FFFF) * 32 + hl];     // x[0] row for pad
            }
#pragma unroll
            for (int k = 0; k < 8; ++k) {
                ax += vv[k] * xv[k].x;
                ay += vv[k] * xv[k].y;
            }
        }
        ax += __shfl_xor(ax, 32);
        ay += __shfl_xor(ay, 32);
        if (half == 0) {
            ((float2*)out)[(size_t)grow * 32 + hl] = make_float2(ax, ay);
        }
    }
}

// ---------- overflow cleanup (runs after gather; expected n==0) ----------
__global__ __launch_bounds__(256) void k_overflow(const float* __restrict__ x,
                                                  const int* __restrict__ ov_cnt,
                                                  const int4* __restrict__ ov,
                                                  float* __restrict__ out) {
    int n = *ov_cnt;
    if (n > OVCAP) n = OVCAP;
    int lane = threadIdx.x & 63;
    int wglobal = (blockIdx.x * 256 + threadIdx.x) >> 6;
    for (int i = wglobal; i < n; i += 64 * 4) {
        int4 e = ov[i];
        atomicAdd(&out[e.x * EMBED_DIM + lane],
                  __int_as_float(e.z) * x[e.y * EMBED_DIM + lane]);
    }
}

// ---------- fallback (ws too small): atomic scatter ----------
__global__ __launch_bounds__(256) void spmm_scatter_kernel(
    const float* __restrict__ x, const float* __restrict__ vals,
    const int* __restrict__ rows, const int* __restrict__ cols,
    float* __restrict__ out) {
    const int wave_in_block = threadIdx.x >> 6;
    const int lane = threadIdx.x & 63;
    const int e = blockIdx.x * 4 + wave_in_block;
    if (e >= N_EDGES) return;
    const float m = vals[e] * x[cols[e] * EMBED_DIM + lane];
    atomicAdd(&out[rows[e] * EMBED_DIM + lane], m);
}

extern "C" void kernel_launch(void* const* d_in, const int* in_sizes, int n_in,
                              void* d_out, int out_size, void* d_ws, size_t ws_size,
                              hipStream_t stream) {
    const float* x    = (const float*)d_in[0];
    const float* vals = (const float*)d_in[1];
    const int*   rows = (const int*)d_in[2];
    const int*   cols = (const int*)d_in[3];
    float* out = (float*)d_out;

    // ws layout: packed[NBKT*CAP] int2 | ov[OVCAP] int4 | gcur[NBKT] | ov_cnt
    const size_t packed_b = (size_t)NBKT * CAP * 8;         // 14,413,824 (16B-aligned)
    const size_t ov_b     = (size_t)OVCAP * 16;
    const size_t need = packed_b + ov_b + ((size_t)NBKT + 1) * 4;
    if (ws_size < need) {
        hipMemsetAsync(out, 0, (size_t)out_size * sizeof(float), stream);
        spmm_scatter_kernel<<<(N_EDGES + 3) / 4, 256, 0, stream>>>(x, vals, rows, cols, out);
        return;
    }

    int2* packed  = (int2*)d_ws;
    int4* ov      = (int4*)((char*)d_ws + packed_b);
    int*  gcur    = (int*)((char*)d_ws + packed_b + ov_b);
    int*  ov_cnt  = gcur + NBKT;

    // single memset: gcur[NBKT] + ov_cnt adjacent
    hipMemsetAsync(gcur, 0, ((size_t)NBKT + 1) * sizeof(int), stream);

    k_binA<<<NTILE, 512, 0, stream>>>(rows, cols, vals, gcur, packed, ov_cnt, ov);
    k_bg<<<NBKT, BG_THREADS, 0, stream>>>(x, gcur, (const int2*)packed, out);
    k_overflow<<<64, 256, 0, stream>>>(x, ov_cnt, ov, out);
}